// Round 4
// baseline (72.165 us; speedup 1.0000x reference)
//
#include <hip/hip_runtime.h>

#define PH 7
#define PW 7
#define SCALE 0.0625f

// Problem constants: feature_map (1,128,56,56) fp32, rois (64,5) fp32,
// out (64,128,7,7) fp32.
#define NB 64
#define NC 128
#define FH 56
#define FW 56

// One block per (b, bin). Lanes = channels. All control flow (bin bounds,
// per-cell dual-ROI mask) is wave-uniform -> scalar branches, zero divergence.
// Out-of-mask cells contribute exactly 0 and are never loaded.
__global__ __launch_bounds__(NC) void DualMaskRoIPool_kernel(
    const float* __restrict__ feat,    // [C,H,W]
    const float* __restrict__ rois1,   // [B,5]
    const float* __restrict__ rois2,   // [B,5]
    float* __restrict__ out)           // [B,C,PH,PW]
{
    const int c   = threadIdx.x;       // 0..127 (2 waves)
    const int bin = blockIdx.x;        // 0..48
    const int b   = blockIdx.y;        // 0..63
    const int i   = bin / PW;
    const int j   = bin % PW;

    // ----- scalar ROI decode (round-half-even, clamp upper bound only) -----
    const float* r1 = rois1 + b * 5;
    const float* r2 = rois2 + b * 5;
    int x1a = (int)rintf(r1[1] * SCALE);
    int y1a = (int)rintf(r1[2] * SCALE);
    int x2a = (int)rintf(r1[3] * SCALE);
    int y2a = (int)rintf(r1[4] * SCALE);
    int x1b = (int)rintf(r2[1] * SCALE);
    int y1b = (int)rintf(r2[2] * SCALE);
    int x2b = (int)rintf(r2[3] * SCALE);
    int y2b = (int)rintf(r2[4] * SCALE);
    if (x1a >= FW) x1a = FW - 1;
    if (y1a >= FH) y1a = FH - 1;
    if (x2a >= FW) x2a = FW - 1;
    if (y2a >= FH) y2a = FH - 1;
    if (x1b >= FW) x1b = FW - 1;
    if (y1b >= FH) y1b = FH - 1;
    if (x2b >= FW) x2b = FW - 1;
    if (y2b >= FH) y2b = FH - 1;

    // ----- union box -----
    const int ux1 = min(x1a, x1b);
    const int uy1 = min(y1a, y1b);
    const int ux2 = max(x2a, x2b);
    const int uy2 = max(y2a, y2b);
    const int h = uy2 - uy1 + 1;   // >= 1
    const int w = ux2 - ux1 + 1;   // >= 1

    // ----- adaptive bin bounds (abs coords, [start,end)); never empty -----
    const int rs = uy1 + (i * h) / PH;
    const int re = uy1 + ((i + 1) * h + PH - 1) / PH;
    const int cs = ux1 + (j * w) / PW;
    const int ce = ux1 + ((j + 1) * w + PW - 1) / PW;

    const float* fc = feat + c * (FH * FW);   // per-lane channel base
    float m = -1e30f;
    bool has_zero = false;   // uniform: any in-bin cell outside both ROIs
    for (int y = rs; y < re; ++y) {
        const bool iny1 = (y >= y1a) && (y <= y2a);
        const bool iny2 = (y >= y1b) && (y <= y2b);
        if (!iny1 && !iny2) { has_zero = true; continue; }  // whole row -> zeros
        const float* frow = fc + y * FW;
        for (int x = cs; x < ce; ++x) {
            const bool in = (iny1 && (x >= x1a) && (x <= x2a)) ||
                            (iny2 && (x >= x1b) && (x <= x2b));
            if (in) m = fmaxf(m, frow[x]);   // uniform branch, per-lane load
            else    has_zero = true;
        }
    }
    if (has_zero) m = fmaxf(m, 0.0f);   // masked-out cells contribute exactly 0

    out[((b * NC + c) * PH + i) * PW + j] = m;
}

extern "C" void kernel_launch(void* const* d_in, const int* in_sizes, int n_in,
                              void* d_out, int out_size, void* d_ws, size_t ws_size,
                              hipStream_t stream) {
    const float* feat  = (const float*)d_in[0];
    const float* rois1 = (const float*)d_in[1];
    const float* rois2 = (const float*)d_in[2];
    float* out = (float*)d_out;

    dim3 grid(PH * PW, NB);   // 49 x 64 blocks, one per (bin, roi)
    DualMaskRoIPool_kernel<<<grid, NC, 0, stream>>>(feat, rois1, rois2, out);
}